// Round 11
// baseline (461.998 us; speedup 1.0000x reference)
//
#include <hip/hip_runtime.h>
#include <hip/hip_fp16.h>
#include <math.h>

#define B_ 32
#define N_ 2048
#define D_ 512

typedef __attribute__((ext_vector_type(8))) _Float16 f16x8;
typedef __attribute__((ext_vector_type(8))) short s16x8;
typedef __attribute__((ext_vector_type(4))) float f32x4;
typedef __attribute__((ext_vector_type(4))) unsigned int u32x4;

__device__ inline unsigned packh2(float lo, float hi) {
    __half l = __float2half_rn(lo), h = __float2half_rn(hi);
    return (unsigned)__half_as_ushort(l) | ((unsigned)__half_as_ushort(h) << 16);
}
__device__ inline unsigned f2bf(float x) {
    unsigned u = __float_as_uint(x);
    return (u + 0x7FFFu + ((u >> 16) & 1u)) >> 16;
}
__device__ inline float bf2f(unsigned h) { return __uint_as_float(h << 16); }

// ---------------------------------------------------------------------------
// Pre-pass (R5 layout, measured 0 conflicts with the 16x16 frag reads):
// tgt_embed fp32 -> fp16 plane, [b][mt 16][kt 16] tiles of 8KB.
// Tile byte (r*64 + s*16) holds K[row=r][k = kt*32 + (s ^ ((r>>1)&3))*8 .. +8].
// ---------------------------------------------------------------------------
__global__ __launch_bounds__(256) void prepass_kernel(
    const float* __restrict__ te, u32x4* __restrict__ kp)
{
    const int idx = blockIdx.x * 256 + threadIdx.x;
    const int b   = idx >> 17;
    const int r17 = idx & 131071;
    const int mt  = r17 >> 13;
    const int kt  = (r17 >> 9) & 15;
    const int o16 = r17 & 511;
    const int r   = o16 >> 2;
    const int s   = o16 & 3;
    const int lg  = s ^ ((r >> 1) & 3);
    const float* src = te + (((size_t)b * N_ + mt * 128 + r) * D_ + kt * 32 + lg * 8);
    const float4 f0 = *(const float4*)src;
    const float4 f1 = *(const float4*)(src + 4);
    u32x4 u;
    u[0] = packh2(f0.x, f0.y);
    u[1] = packh2(f0.z, f0.w);
    u[2] = packh2(f1.x, f1.y);
    u[3] = packh2(f1.z, f1.w);
    kp[idx] = u;
}

// ---------------------------------------------------------------------------
// KV-split attention: 1024 blocks x 256 thr (4 waves), __launch_bounds__(256,3)
// -> 3 blocks/CU (12 waves, reg-capped; Q is STREAMED from fp32 global with a
// 2-tile lookahead instead of held in 128 VGPRs). Block = (batch b, 128 q-rows
// msl, kv-half kvh): scans 8 KV chunks of 128 rows. K flows in 16KB groups
// (2 tiles) through a 2-half LDS ring; one barrier per group; stage g+1 right
// after the barrier. Per-row online-softmax state (m,l,ax,ay,az) written to
// global mlv records; a merge kernel combines the two kv-halves.
// mfma_f32_16x16x32_f16(A=K, B=Q): lane owns q-row -> lane-local softmax.
// ---------------------------------------------------------------------------
__global__ __launch_bounds__(256, 3) void attn_kv_kernel(
    const float* __restrict__ tgt, const float* __restrict__ src_embed,
    const u32x4* __restrict__ kp, float* __restrict__ mlv)
{
    __shared__ f16x8 Kbuf[2][2][512];   // 32 KB: 2 halves x 2 tiles x 8KB
    __shared__ float4 TsB[2][128];      // 4 KB tgt coords, per-chunk DB

    const int tid  = threadIdx.x;
    const int wv   = tid >> 6;
    const int lane = tid & 63;
    const int lr   = lane & 15;
    const int lg   = lane >> 4;
    const int sxb  = (lg ^ ((lr >> 1) & 3)) << 4;
    char* KbufB = (char*)&Kbuf[0][0][0];

    const int xcd  = blockIdx.x & 7;
    const int idx  = blockIdx.x >> 3;          // 0..127
    const int b    = xcd * 4 + (idx >> 5);     // 4 batches per XCD
    const int r5   = idx & 31;
    const int msl  = r5 >> 1;                  // 0..15 q-chunk
    const int kvh  = r5 & 1;                   // kv half
    const int n0   = msl * 128;
    const int mc0  = kvh * 8;                  // first KV chunk

    const float QSC = 0.044194173824159216f * 1.4426950408889634f;
    const float* qp0 = src_embed + ((size_t)b * N_ + n0 + wv * 32 + lr) * D_ + lg * 8;
    const float* qp1 = qp0 + (size_t)16 * D_;

    // Q streaming state: current frags + next-tile fp32 buffer
    f16x8 Qc0, Qc1;
    float4 qb0, qb1, qb2, qb3;

#define QLOAD(t_) do {                                                         \
    const int _ko = ((t_) & 15) * 32;                                          \
    qb0 = *(const float4*)(qp0 + _ko);                                         \
    qb1 = *(const float4*)(qp0 + _ko + 4);                                     \
    qb2 = *(const float4*)(qp1 + _ko);                                         \
    qb3 = *(const float4*)(qp1 + _ko + 4);                                     \
} while (0)

#define QCVT() do {                                                            \
    u32x4 _u;                                                                  \
    _u[0] = packh2(qb0.x * QSC, qb0.y * QSC);                                  \
    _u[1] = packh2(qb0.z * QSC, qb0.w * QSC);                                  \
    _u[2] = packh2(qb1.x * QSC, qb1.y * QSC);                                  \
    _u[3] = packh2(qb1.z * QSC, qb1.w * QSC);                                  \
    Qc0 = __builtin_bit_cast(f16x8, _u);                                       \
    _u[0] = packh2(qb2.x * QSC, qb2.y * QSC);                                  \
    _u[1] = packh2(qb2.z * QSC, qb2.w * QSC);                                  \
    _u[2] = packh2(qb3.x * QSC, qb3.y * QSC);                                  \
    _u[3] = packh2(qb3.z * QSC, qb3.w * QSC);                                  \
    Qc1 = __builtin_bit_cast(f16x8, _u);                                       \
} while (0)

    // stage tile t (block-local 0..127) into ring half ((t>>1)&1), slot (t&1)
#define STAGE_TILE(t_) do {                                                    \
    const int _mc = mc0 + ((t_) >> 4);                                         \
    const u32x4* _g = kp + ((((size_t)b * 16 + _mc) * 16 + ((t_) & 15)) << 9); \
    f16x8* _d = &Kbuf[((t_) >> 1) & 1][(t_) & 1][wv * 64];                     \
    __builtin_amdgcn_global_load_lds(                                          \
        (const __attribute__((address_space(1))) void*)(_g + tid),             \
        (__attribute__((address_space(3))) void*)_d, 16, 0, 0);                \
    __builtin_amdgcn_global_load_lds(                                          \
        (const __attribute__((address_space(1))) void*)(_g + 256 + tid),       \
        (__attribute__((address_space(3))) void*)(_d + 256), 16, 0, 0);        \
} while (0)

    // ---- prologue ----------------------------------------------------------
    QLOAD(0); QCVT(); QLOAD(1);
    STAGE_TILE(0); STAGE_TILE(1);
    if (tid < 128) {
        const float* tp = tgt + ((size_t)b * N_ + mc0 * 128 + tid) * 3;
        TsB[0][tid] = make_float4(tp[0], tp[1], tp[2], 0.f);
    }

    float m_s[2] = {-1e30f, -1e30f}, l_s[2] = {0.f, 0.f};
    float axs[2] = {0.f, 0.f}, ays[2] = {0.f, 0.f}, azs[2] = {0.f, 0.f};
    f32x4 acc0[8], acc1[8];

#define MFMA_TILE(halfb_, ti_) do {                                            \
    const char* _ab = KbufB + (halfb_) * 16384 + (ti_) * 8192 + lr * 64 + sxb; \
    _Pragma("unroll")                                                          \
    for (int nf = 0; nf < 8; ++nf) {                                           \
        const f16x8 a = *(const f16x8*)(_ab + nf * 1024);                      \
        acc0[nf] = __builtin_amdgcn_mfma_f32_16x16x32_f16(a, Qc0, acc0[nf], 0, 0, 0); \
        acc1[nf] = __builtin_amdgcn_mfma_f32_16x16x32_f16(a, Qc1, acc1[nf], 0, 0, 0); \
    }                                                                          \
} while (0)

    for (int mcl = 0; mcl < 8; ++mcl) {
        for (int g = 0; g < 8; ++g) {
            const int t = (mcl << 4) | (g << 1);   // first tile of group
            __syncthreads();                       // half (g&1) ready
            if (t < 126) { STAGE_TILE(t + 2); STAGE_TILE(t + 3); }
            float tv0 = 0.f, tv1 = 0.f, tv2 = 0.f;
            const bool pf = (g == 7) && (mcl < 7) && (tid < 128);
            if (pf) {
                const float* tp = tgt +
                    ((size_t)b * N_ + (mc0 + mcl + 1) * 128 + tid) * 3;
                tv0 = tp[0]; tv1 = tp[1]; tv2 = tp[2];
            }
            if (g == 0) {
#pragma unroll
                for (int nf = 0; nf < 8; ++nf) {
                    acc0[nf] = (f32x4){0.f, 0.f, 0.f, 0.f};
                    acc1[nf] = (f32x4){0.f, 0.f, 0.f, 0.f};
                }
            }
            __builtin_amdgcn_s_setprio(1);
            MFMA_TILE(g & 1, 0);                   // tile t with Qc(t)
            QCVT();                                // frags for t+1
            QLOAD(t + 2);
            MFMA_TILE(g & 1, 1);                   // tile t+1
            QCVT();                                // frags for t+2
            QLOAD(t + 3);
            __builtin_amdgcn_s_setprio(0);
            if (pf)
                TsB[(mcl + 1) & 1][tid] = make_float4(tv0, tv1, tv2, 0.f);

            if (g == 7) {
                // ---- online-softmax epilogue for this 128-row KV chunk -----
                const float4* Ts = &TsB[mcl & 1][0];
                float mx0 = -1e30f, mx1 = -1e30f;
#pragma unroll
                for (int nf = 0; nf < 8; ++nf)
#pragma unroll
                    for (int r4 = 0; r4 < 4; ++r4) {
                        mx0 = fmaxf(mx0, acc0[nf][r4]);
                        mx1 = fmaxf(mx1, acc1[nf][r4]);
                    }
                mx0 = fmaxf(mx0, __shfl_xor(mx0, 16)); mx0 = fmaxf(mx0, __shfl_xor(mx0, 32));
                mx1 = fmaxf(mx1, __shfl_xor(mx1, 16)); mx1 = fmaxf(mx1, __shfl_xor(mx1, 32));
                const float mn0 = fmaxf(m_s[0], mx0), mn1 = fmaxf(m_s[1], mx1);
                const float c0 = exp2f(m_s[0] - mn0), c1 = exp2f(m_s[1] - mn1);
                l_s[0] *= c0; axs[0] *= c0; ays[0] *= c0; azs[0] *= c0; m_s[0] = mn0;
                l_s[1] *= c1; axs[1] *= c1; ays[1] *= c1; azs[1] *= c1; m_s[1] = mn1;
                float l0 = 0.f, x0 = 0.f, y0 = 0.f, z0 = 0.f;
                float l1 = 0.f, x1 = 0.f, y1 = 0.f, z1 = 0.f;
#pragma unroll
                for (int nf = 0; nf < 8; ++nf)
#pragma unroll
                    for (int r4 = 0; r4 < 4; ++r4) {
                        const float4 tv = Ts[nf * 16 + lg * 4 + r4];
                        const float p0 = exp2f(acc0[nf][r4] - mn0);
                        const float p1 = exp2f(acc1[nf][r4] - mn1);
                        l0 += p0; x0 = fmaf(p0, tv.x, x0); y0 = fmaf(p0, tv.y, y0); z0 = fmaf(p0, tv.z, z0);
                        l1 += p1; x1 = fmaf(p1, tv.x, x1); y1 = fmaf(p1, tv.y, y1); z1 = fmaf(p1, tv.z, z1);
                    }
                l_s[0] += l0; axs[0] += x0; ays[0] += y0; azs[0] += z0;
                l_s[1] += l1; axs[1] += x1; ays[1] += y1; azs[1] += z1;
            }
        }
    }
#undef MFMA_TILE
#undef STAGE_TILE
#undef QCVT
#undef QLOAD

    // ---- finalize: fold lane-replicas, write per-row (m,l,ax,ay,az) --------
#pragma unroll
    for (int qf = 0; qf < 2; ++qf) {
        float lt = l_s[qf], x = axs[qf], y = ays[qf], z = azs[qf];
        lt += __shfl_xor(lt, 16); lt += __shfl_xor(lt, 32);
        x  += __shfl_xor(x, 16);  x  += __shfl_xor(x, 32);
        y  += __shfl_xor(y, 16);  y  += __shfl_xor(y, 32);
        z  += __shfl_xor(z, 16);  z  += __shfl_xor(z, 32);
        if (lg == 0) {
            const int row = wv * 32 + qf * 16 + lr;
            float* rp = mlv +
                (((size_t)(b * 16 + msl) * 2 + kvh) * 128 + row) * 5;
            rp[0] = m_s[qf]; rp[1] = lt; rp[2] = x; rp[3] = y; rp[4] = z;
        }
    }
}

// ---------------------------------------------------------------------------
// Merge the two kv-half records per row; form 15 partials per q-chunk block.
// ---------------------------------------------------------------------------
__global__ void merge_kernel(const float* __restrict__ src,
                             const float* __restrict__ mlv,
                             float* __restrict__ partials)
{
    __shared__ double red[2][15];
    const int blk = blockIdx.x;        // 0..511 = b*16 + msl
    const int b   = blk >> 4;
    const int msl = blk & 15;
    const int tid = threadIdx.x;       // 128
    const int wv  = tid >> 6;
    const int lane = tid & 63;

    const float* r0 = mlv + ((size_t)blk * 2 + 0) * 128 * 5 + (size_t)tid * 5;
    const float* r1 = mlv + ((size_t)blk * 2 + 1) * 128 * 5 + (size_t)tid * 5;
    const float m0 = r0[0], l0f = r0[1], x0 = r0[2], y0 = r0[3], z0 = r0[4];
    const float m1 = r1[0], l1f = r1[1], x1 = r1[2], y1 = r1[3], z1 = r1[4];
    const float M  = fmaxf(m0, m1);
    const double w0 = (double)exp2f(m0 - M), w1 = (double)exp2f(m1 - M);
    const double l  = (double)l0f * w0 + (double)l1f * w1;
    const double ax = (double)x0 * w0 + (double)x1 * w1;
    const double ay = (double)y0 * w0 + (double)y1 * w1;
    const double az = (double)z0 * w0 + (double)z1 * w1;
    const double inv = 1.0 / l;
    const double m0d = ax * inv, m1d = ay * inv, m2d = az * inv;

    const int n = msl * 128 + tid;
    const float* sp = src + ((size_t)b * N_ + n) * 3;
    const double s0 = sp[0], s1 = sp[1], s2 = sp[2];

    double dl[15];
    dl[0] = s0;  dl[1] = s1;  dl[2] = s2;
    dl[3] = m0d; dl[4] = m1d; dl[5] = m2d;
    dl[6]  = s0 * m0d; dl[7]  = s0 * m1d; dl[8]  = s0 * m2d;
    dl[9]  = s1 * m0d; dl[10] = s1 * m1d; dl[11] = s1 * m2d;
    dl[12] = s2 * m0d; dl[13] = s2 * m1d; dl[14] = s2 * m2d;

#pragma unroll
    for (int i = 0; i < 15; ++i) {
        double v = dl[i];
        for (int off = 1; off < 64; off <<= 1) v += __shfl_xor(v, off);
        dl[i] = v;
    }
    if (lane == 0) {
#pragma unroll
        for (int i = 0; i < 15; ++i) red[wv][i] = dl[i];
    }
    __syncthreads();
    if (tid < 15)
        partials[(size_t)blk * 15 + tid] = (float)(red[0][tid] + red[1][tid]);
}

// ---------------------------------------------------------------------------
// Fallback (proven round-2 kernel): bf16 hi/lo 3-product, 1024 blocks.
// ---------------------------------------------------------------------------
__global__ __launch_bounds__(256, 2) void attn_v2_kernel(
    const float* __restrict__ src, const float* __restrict__ tgt,
    const float* __restrict__ src_embed, const float* __restrict__ tgt_embed,
    float* __restrict__ partials)
{
    __shared__ short Khi_s[128 * 64];
    __shared__ short Klo_s[128 * 64];
    __shared__ float4 Ts4[128];
    __shared__ double red[64][15];

    char* KhiB = (char*)Khi_s;
    char* KloB = (char*)Klo_s;

    const int w    = blockIdx.x;
    const int xcd  = w & 7;
    const int idx  = w >> 3;
    const int b    = xcd * 4 + (idx >> 5);
    const int n0   = (idx & 31) * 64;
    const int blk  = b * 32 + (idx & 31);

    const int tid  = threadIdx.x;
    const int wv   = tid >> 6;
    const int lane = tid & 63;
    const int lr   = lane & 15;
    const int lg   = lane >> 4;
    const unsigned swl = (unsigned)((lr & 7) << 4);

    const float scale = 0.044194173824159216f;
    const float* kbase = tgt_embed + (size_t)b * N_ * D_;

    const int qrow = n0 + wv * 16 + lr;
    const float* qp = src_embed + ((size_t)b * N_ + qrow) * D_ + lg * 8;
    s16x8 qhi[16], qlo[16];
#pragma unroll
    for (int s = 0; s < 16; ++s) {
        const float4 f0 = *reinterpret_cast<const float4*>(qp + s * 32);
        const float4 f1 = *reinterpret_cast<const float4*>(qp + s * 32 + 4);
        const float x[8] = {f0.x, f0.y, f0.z, f0.w, f1.x, f1.y, f1.z, f1.w};
#pragma unroll
        for (int i = 0; i < 8; ++i) {
            const float v = x[i] * scale;
            const unsigned h = f2bf(v);
            qhi[s][i] = (short)h;
            qlo[s][i] = (short)f2bf(v - bf2f(h));
        }
    }

    float m_run = -1e30f, l_run = 0.f, a0 = 0.f, a1 = 0.f, a2 = 0.f;
    const int srow = tid >> 1;
    const int shalf = tid & 1;
    const unsigned swr = (unsigned)((srow & 7) << 4);

    for (int m0 = 0; m0 < N_; m0 += 128) {
        f32x4 acc[8];
#pragma unroll
        for (int nf = 0; nf < 8; ++nf) acc[nf] = (f32x4){0.f, 0.f, 0.f, 0.f};

#pragma unroll
        for (int kt = 0; kt < 8; ++kt) {
            __syncthreads();
            {
                const float* gp = kbase + (size_t)(m0 + srow) * D_ + kt * 64 + shalf * 32;
#pragma unroll
                for (int grp = 0; grp < 4; ++grp) {
                    const float4 fa = *reinterpret_cast<const float4*>(gp + grp * 8);
                    const float4 fb = *reinterpret_cast<const float4*>(gp + grp * 8 + 4);
                    const float x[8] = {fa.x, fa.y, fa.z, fa.w, fb.x, fb.y, fb.z, fb.w};
                    s16x8 hi, lo;
#pragma unroll
                    for (int i = 0; i < 8; ++i) {
                        const unsigned h = f2bf(x[i]);
                        hi[i] = (short)h;
                        lo[i] = (short)f2bf(x[i] - bf2f(h));
                    }
                    const unsigned off = (unsigned)srow * 128u +
                        (((unsigned)(shalf * 64 + grp * 16)) ^ swr);
                    *reinterpret_cast<s16x8*>(KhiB + off) = hi;
                    *reinterpret_cast<s16x8*>(KloB + off) = lo;
                }
                if (kt == 0 && tid < 128) {
                    const float* tp = tgt + ((size_t)b * N_ + m0 + tid) * 3;
                    Ts4[tid] = make_float4(tp[0], tp[1], tp[2], 0.f);
                }
            }
            __syncthreads();
#pragma unroll
            for (int ks = 0; ks < 2; ++ks) {
                const int s = kt * 2 + ks;
                const unsigned kb = ((unsigned)(lg * 16 + ks * 64)) ^ swl;
#pragma unroll
                for (int nf = 0; nf < 8; ++nf) {
                    const unsigned off = (unsigned)(nf * 16 + lr) * 128u + kb;
                    const s16x8 ah = *reinterpret_cast<const s16x8*>(KhiB + off);
                    const s16x8 al = *reinterpret_cast<const s16x8*>(KloB + off);
                    acc[nf] = __builtin_amdgcn_mfma_f32_16x16x32_bf16(ah, qhi[s], acc[nf], 0, 0, 0);
                    acc[nf] = __builtin_amdgcn_mfma_f32_16x16x32_bf16(al, qhi[s], acc[nf], 0, 0, 0);
                    acc[nf] = __builtin_amdgcn_mfma_f32_16x16x32_bf16(ah, qlo[s], acc[nf], 0, 0, 0);
                }
            }
        }

        float mx = -1e30f;
#pragma unroll
        for (int nf = 0; nf < 8; ++nf)
#pragma unroll
            for (int r = 0; r < 4; ++r) mx = fmaxf(mx, acc[nf][r]);
        mx = fmaxf(mx, __shfl_xor(mx, 16));
        mx = fmaxf(mx, __shfl_xor(mx, 32));

        const float mnew = fmaxf(m_run, mx);
        const float corr = __expf(m_run - mnew);
        l_run *= corr; a0 *= corr; a1 *= corr; a2 *= corr;

        float ps = 0.f, p0 = 0.f, p1 = 0.f, p2 = 0.f;
#pragma unroll
        for (int nf = 0; nf < 8; ++nf)
#pragma unroll
            for (int r = 0; r < 4; ++r) {
                const float p = __expf(acc[nf][r] - mnew);
                const int n = nf * 16 + lg * 4 + r;
                const float4 tv = Ts4[n];
                ps += p;
                p0 = fmaf(p, tv.x, p0);
                p1 = fmaf(p, tv.y, p1);
                p2 = fmaf(p, tv.z, p2);
            }
        l_run += ps; a0 += p0; a1 += p1; a2 += p2;
        m_run = mnew;
    }

    l_run += __shfl_xor(l_run, 16); l_run += __shfl_xor(l_run, 32);
    a0 += __shfl_xor(a0, 16); a0 += __shfl_xor(a0, 32);
    a1 += __shfl_xor(a1, 16); a1 += __shfl_xor(a1, 32);
    a2 += __shfl_xor(a2, 16); a2 += __shfl_xor(a2, 32);

    __syncthreads();
    if (lg == 0) {
        const float inv = 1.0f / l_run;
        const double mx0 = (double)(a0 * inv);
        const double mx1 = (double)(a1 * inv);
        const double mx2 = (double)(a2 * inv);
        const float* sp = src + ((size_t)b * N_ + qrow) * 3;
        const double s0 = sp[0], s1 = sp[1], s2 = sp[2];
        double* rp = red[wv * 16 + lr];
        rp[0] = s0;  rp[1] = s1;  rp[2] = s2;
        rp[3] = mx0; rp[4] = mx1; rp[5] = mx2;
        rp[6]  = s0 * mx0; rp[7]  = s0 * mx1; rp[8]  = s0 * mx2;
        rp[9]  = s1 * mx0; rp[10] = s1 * mx1; rp[11] = s1 * mx2;
        rp[12] = s2 * mx0; rp[13] = s2 * mx1; rp[14] = s2 * mx2;
    }
    __syncthreads();
    if (tid < 15) {
        double sum = 0.0;
        for (int j = 0; j < 64; ++j) sum += red[j][tid];
        partials[(size_t)blk * 15 + tid] = (float)sum;
    }
}

// ---------------------------------------------------------------------------
// Kabsch (fp64 internals, float partials), nbb = partial blocks per batch.
// ---------------------------------------------------------------------------
__global__ void kabsch_kernel(const float* __restrict__ partials,
                              float* __restrict__ out, int nbb)
{
    const int b = threadIdx.x;
    if (b >= B_) return;

    double acc[15];
#pragma unroll
    for (int i = 0; i < 15; ++i) acc[i] = 0.0;
    for (int rb = 0; rb < nbb; ++rb) {
        const float* p = partials + ((size_t)b * nbb + rb) * 15;
#pragma unroll
        for (int i = 0; i < 15; ++i) acc[i] += (double)p[i];
    }

    const double invN = 1.0 / (double)N_;
    const double S[3] = {acc[0], acc[1], acc[2]};
    const double M[3] = {acc[3], acc[4], acc[5]};
    double H[3][3];
    for (int c = 0; c < 3; ++c)
        for (int d = 0; d < 3; ++d)
            H[c][d] = acc[6 + c * 3 + d] - S[c] * M[d] * invN;

    double A[3][3];
    for (int i = 0; i < 3; ++i)
        for (int j = 0; j < 3; ++j)
            A[i][j] = H[0][i] * H[0][j] + H[1][i] * H[1][j] + H[2][i] * H[2][j];

    double V[3][3] = {{1, 0, 0}, {0, 1, 0}, {0, 0, 1}};
    const int PQ[3][2] = {{0, 1}, {0, 2}, {1, 2}};
    for (int sweep = 0; sweep < 20; ++sweep) {
        const double off = fabs(A[0][1]) + fabs(A[0][2]) + fabs(A[1][2]);
        if (off < 1e-24) break;
        for (int pi = 0; pi < 3; ++pi) {
            const int p = PQ[pi][0], q = PQ[pi][1], rr = 3 - p - q;
            const double apq = A[p][q];
            if (fabs(apq) < 1e-300) continue;
            const double theta = (A[q][q] - A[p][p]) / (2.0 * apq);
            const double tt = (theta >= 0.0 ? 1.0 : -1.0) /
                              (fabs(theta) + sqrt(1.0 + theta * theta));
            const double c = 1.0 / sqrt(1.0 + tt * tt);
            const double sn = tt * c;
            const double app = A[p][p], aqq = A[q][q];
            const double arp = A[rr][p], arq = A[rr][q];
            A[p][p] = app - tt * apq;
            A[q][q] = aqq + tt * apq;
            A[p][q] = A[q][p] = 0.0;
            A[rr][p] = A[p][rr] = c * arp - sn * arq;
            A[rr][q] = A[q][rr] = sn * arp + c * arq;
            for (int k = 0; k < 3; ++k) {
                const double vkp = V[k][p], vkq = V[k][q];
                V[k][p] = c * vkp - sn * vkq;
                V[k][q] = sn * vkp + c * vkq;
            }
        }
    }

    double R[3][3] = {{0, 0, 0}, {0, 0, 0}, {0, 0, 0}};
    for (int i = 0; i < 3; ++i) {
        const double lam = A[i][i];
        const double sig = sqrt(lam > 0.0 ? lam : 0.0);
        const double inv = 1.0 / (sig > 1e-30 ? sig : 1e-30);
        double wv[3];
        for (int c = 0; c < 3; ++c)
            wv[c] = H[c][0] * V[0][i] + H[c][1] * V[1][i] + H[c][2] * V[2][i];
        for (int r = 0; r < 3; ++r)
            for (int c = 0; c < 3; ++c)
                R[r][c] += V[r][i] * wv[c] * inv;
    }

    const double det =
        R[0][0] * (R[1][1] * R[2][2] - R[1][2] * R[2][1]) -
        R[0][1] * (R[1][0] * R[2][2] - R[1][2] * R[2][0]) +
        R[0][2] * (R[1][0] * R[2][1] - R[1][1] * R[2][0]);
    if (det < 0.0) {
        R[2][0] = -R[2][0]; R[2][1] = -R[2][1]; R[2][2] = -R[2][2];
    }

    double t[3];
    for (int c = 0; c < 3; ++c)
        t[c] = M[c] * invN -
               (R[c][0] * S[0] + R[c][1] * S[1] + R[c][2] * S[2]) * invN;

    for (int r = 0; r < 3; ++r)
        for (int c = 0; c < 3; ++c)
            out[(size_t)b * 9 + r * 3 + c] = (float)R[r][c];
    for (int c = 0; c < 3; ++c)
        out[(size_t)B_ * 9 + (size_t)b * 3 + c] = (float)t[c];
}

// ---------------------------------------------------------------------------
extern "C" void kernel_launch(void* const* d_in, const int* in_sizes, int n_in,
                              void* d_out, int out_size, void* d_ws, size_t ws_size,
                              hipStream_t stream) {
    const float* src = (const float*)d_in[0];
    const float* tgt = (const float*)d_in[1];
    const float* se  = (const float*)d_in[2];
    const float* te  = (const float*)d_in[3];
    float* out = (float*)d_out;

    // ws layout: [0, 30720) partials (512x15 f32); [32768, +2.62MB) mlv
    // (1024 x 128 rows x 5 f32); then fp16 K plane (64 MB, 16B aligned).
    const size_t MLV_OFF = 32768;
    const size_t MLV_SZ  = (size_t)1024 * 128 * 5 * 4;   // 2,621,440
    const size_t KP_OFF  = MLV_OFF + MLV_SZ;             // 2,654,208
    const size_t need    = KP_OFF + (size_t)B_ * N_ * D_ * 2;  // 69,763,072

    if (ws_size >= need) {
        u32x4* kp  = (u32x4*)((char*)d_ws + KP_OFF);
        float* mlv = (float*)((char*)d_ws + MLV_OFF);
        prepass_kernel<<<dim3(16384), dim3(256), 0, stream>>>(te, kp);
        attn_kv_kernel<<<dim3(1024), dim3(256), 0, stream>>>(tgt, se, kp, mlv);
        merge_kernel<<<dim3(512), dim3(128), 0, stream>>>(src, mlv, (float*)d_ws);
        kabsch_kernel<<<dim3(1), dim3(64), 0, stream>>>((float*)d_ws, out, 16);
    } else {
        attn_v2_kernel<<<dim3(1024), dim3(256), 0, stream>>>(
            src, tgt, se, te, (float*)d_ws);
        kabsch_kernel<<<dim3(1), dim3(64), 0, stream>>>((float*)d_ws, out, 32);
    }
}